// Round 2
// baseline (172.068 us; speedup 1.0000x reference)
//
#include <hip/hip_runtime.h>
#include <hip/hip_bf16.h>
#include <hip/hip_cooperative_groups.h>

namespace cg = cooperative_groups;

// RelationNetwork fused pipeline, bf16 MFMA (gfx950).
//
// r10: SINGLE cooperative launch. Rationale: rocprof shows the timed window
// is dominated by two ~41us 256MiB harness poison fills (80% HBM peak);
// our controllable portion is launch gaps + kernel latency. So:
//  - every block issues its X loads into regs at t=0 (HBM latency hidden
//    behind prep);
//  - blocks 0..95 do the weight transposes (LDS scratch overlays the
//    not-yet-live Xs region), __threadfence();
//  - one grid.sync() (256 blocks x 118KB LDS = exactly 1 block/CU ->
//    co-residency guaranteed, cooperative launch valid);
//  - then the unchanged per-b pipeline: UV mini-GEMM -> h1 -> h1@W2T ->
//    column sums -> f_phi -> out.
//
// Factorizations (carried):
//  (1) pair@W1 = u[i]+v[j]  -> per-b 16x512x512 mini-GEMM in LDS.
//  (2) ctx-ctx pair sum is choice-invariant -> computed once per b.
//  (3) f_phi fused (agg rows live in LDS).
//
// ws layout (bytes):
//   [0,        524288)   Wp   bf16 [512][512]  Wp[j][k]=W1'[k][j]
//   [524288,   655360)   W2T  bf16 [256][256]
//   [655360,   786432)   W3T  bf16 [256][256]

typedef __bf16 bf16_t;
typedef bf16_t bf16x8 __attribute__((ext_vector_type(8)));
typedef bf16_t bf16x4 __attribute__((ext_vector_type(4)));
typedef float f32x4 __attribute__((ext_vector_type(4)));

#define MFMA16(a, b, c) __builtin_amdgcn_mfma_f32_16x16x32_bf16((a), (b), (c), 0, 0, 0)

// LDS map (118016 B total):
//   [0,     16640)  UVs bf16 [16][520]   (prep scratch Ts f32[64][65] overlays
//                                          this region before UVs is live)
//   [16640, 118016) h1  bf16 [192][264]
//     overlays: Xs bf16 [16][520] @16640 (phase-1 A-tile, dead after phase 1)
//               S f32 [9][256] @16640; Ag bf16 [16][264] @+9216; red @+17664
__global__ __launch_bounds__(512) void fused_kernel(
    const float* __restrict__ ctx, const float* __restrict__ cho,
    const float* __restrict__ W1, const float* __restrict__ W2,
    const float* __restrict__ W3, bf16_t* __restrict__ Wp,
    bf16_t* __restrict__ W2T, bf16_t* __restrict__ W3T,
    const float* __restrict__ b1, const float* __restrict__ b2,
    const float* __restrict__ b3, const float* __restrict__ W4,
    const float* __restrict__ b4, float* __restrict__ out) {
  __shared__ char smem[118016];
  bf16_t (*UVs)[520] = (bf16_t(*)[520])smem;
  float  (*Ts)[65]   = (float(*)[65])smem;              // prep scratch (16640 B)
  bf16_t (*Xs)[520]  = (bf16_t(*)[520])(smem + 16640);
  bf16_t (*h1)[264]  = (bf16_t(*)[264])(smem + 16640);
  float  (*S)[256]   = (float(*)[256])(smem + 16640);
  bf16_t (*Ag)[264]  = (bf16_t(*)[264])(smem + 16640 + 9216);
  float  (*red)[8]   = (float(*)[8])(smem + 16640 + 9216 + 8448);
  const int b = blockIdx.x;
  const int t = threadIdx.x;
  const int lane = t & 63;
  const int w = t >> 6;
  const int col = lane & 15;
  const int quad = lane >> 4;

  // ---- Phase 0: issue this block's X loads into regs (latency hides under
  // prep). 32 thr/row, 16 floats each, 64 B/lane coalesced. ----
  const int xrow = t >> 5;          // 0..15
  const int xc0 = (t & 31) * 16;
  const float* xsrc = (xrow < 8) ? ctx + ((size_t)b * 8 + xrow) * 512
                                 : cho + ((size_t)b * 8 + (xrow - 8)) * 512;
  const f32x4 x0 = *(const f32x4*)(xsrc + xc0);
  const f32x4 x1 = *(const f32x4*)(xsrc + xc0 + 4);
  const f32x4 x2 = *(const f32x4*)(xsrc + xc0 + 8);
  const f32x4 x3 = *(const f32x4*)(xsrc + xc0 + 12);

  // ---- Prep (blocks 0..95): weight transposes via LDS tile. Ts fp32
  // [64][65]: transpose-read bank stride 65%32=1 -> 2-way only. ----
  if (b < 96) {
    const int r = t >> 6;          // 0..7
    const int c = t & 63;
    const float* srcP;
    bf16_t* dstP;
    int srcRow, srcCol, dr0, dc0, dstride;
    if (b < 64) {                  // Wp tile: tk = b>>3, tj = b&7
      const int k0 = (b >> 3) * 64, j0 = (b & 7) * 64;
      srcP = W1; dstP = Wp; dstride = 512;
      srcRow = (j0 < 256) ? k0 : 512 + k0;
      srcCol = (j0 < 256) ? j0 : j0 - 256;
      dr0 = j0; dc0 = k0;
    } else if (b < 80) {           // W2T tile
      const int s = b - 64;
      const int k0 = (s >> 2) * 64, n0 = (s & 3) * 64;
      srcP = W2; dstP = W2T; dstride = 256;
      srcRow = k0; srcCol = n0; dr0 = n0; dc0 = k0;
    } else {                       // W3T tile
      const int s = b - 80;
      const int k0 = (s >> 2) * 64, n0 = (s & 3) * 64;
      srcP = W3; dstP = W3T; dstride = 256;
      srcRow = k0; srcCol = n0; dr0 = n0; dc0 = k0;
    }
    for (int i = 0; i < 8; ++i) {           // 8 iters x 8 rows = 64 rows
      const int a = i * 8 + r;
      Ts[a][c] = srcP[(size_t)(srcRow + a) * 256 + srcCol + c];
    }
    __syncthreads();
    for (int i = 0; i < 8; ++i) {
      const int j = i * 8 + r;
      dstP[(size_t)(dr0 + j) * dstride + dc0 + c] = (bf16_t)Ts[c][j];
    }
    __threadfence();               // make ws writes device-visible
  }
  cg::this_grid().sync();          // weights ready everywhere

  // ---- Phase 1a: X regs -> Xs (bf16). ----
  {
    bf16x8 y0, y1;
    for (int e = 0; e < 4; ++e) { y0[e] = (bf16_t)x0[e]; y0[4 + e] = (bf16_t)x1[e]; }
    for (int e = 0; e < 4; ++e) { y1[e] = (bf16_t)x2[e]; y1[4 + e] = (bf16_t)x3[e]; }
    *(bf16x8*)(&Xs[xrow][xc0]) = y0;
    *(bf16x8*)(&Xs[xrow][xc0 + 8]) = y1;
  }
  __syncthreads();

  // ---- Phase 1b: UVs = X @ Wp^T (M=16, N=512, K=512). Wave w owns n in
  // [w*64, w*64+64): streams a contiguous 64-row slab of Wp from L2. ----
  {
    f32x4 acc1[4] = {};
    for (int ks = 0; ks < 16; ++ks) {
      const int k = ks * 32 + quad * 8;
      const bf16x8 af = *(const bf16x8*)(&Xs[col][k]);
      for (int nt = 0; nt < 4; ++nt) {
        const int n = w * 64 + nt * 16 + col;
        const bf16x8 bfr = *(const bf16x8*)(Wp + (size_t)n * 512 + k);
        acc1[nt] = MFMA16(af, bfr, acc1[nt]);
      }
    }
    for (int nt = 0; nt < 4; ++nt) {
      const int n = w * 64 + nt * 16 + col;
      for (int reg = 0; reg < 4; ++reg)
        UVs[quad * 4 + reg][n] = (bf16_t)acc1[nt][reg];
    }
  }
  __syncthreads();   // UVs ready; Xs dead -> h1 may overlay

  // ---- Phase 2: h1 = relu(u[i]+v[j]+b1), all LDS. 2 thr/row x 128 cols. ----
  if (t < 384) {
    const int sr = t >> 1;
    const int sc0 = (t & 1) * 128;
    const bf16_t* su = nullptr;
    const bf16_t* sv = nullptr;
    if (sr < 56) {
      const int i = sr / 7;
      const int jj = sr - i * 7;
      const int j = jj + (jj >= i ? 1 : 0);
      su = UVs[i];
      sv = UVs[j] + 256;
    } else if (sr >= 64) {
      const int ch = (sr - 64) >> 4;
      const int rr = (sr - 64) & 15;
      if (rr < 8) { su = UVs[8 + ch]; sv = UVs[rr] + 256; }
      else        { su = UVs[rr - 8]; sv = UVs[8 + ch] + 256; }
    }
    if (su) {
      for (int c = sc0; c < sc0 + 128; c += 8) {
        const bf16x8 u8 = *(const bf16x8*)(su + c);
        const bf16x8 v8 = *(const bf16x8*)(sv + c);
        const f32x4 bb0 = *(const f32x4*)(b1 + c);
        const f32x4 bb1 = *(const f32x4*)(b1 + c + 4);
        bf16x8 y;
        for (int e = 0; e < 4; ++e)
          y[e] = (bf16_t)fmaxf((float)u8[e] + (float)v8[e] + bb0[e], 0.0f);
        for (int e = 0; e < 4; ++e)
          y[4 + e] = (bf16_t)fmaxf((float)u8[4 + e] + (float)v8[4 + e] + bb1[e], 0.0f);
        *(bf16x8*)(&h1[sr][c]) = y;
      }
    } else {               // zero-pad rows 56..63
      for (int c = sc0; c < sc0 + 128; c += 8)
        *(bf16x8*)(&h1[sr][c]) = (bf16x8)0.0f;
    }
  }
  __syncthreads();

  // ---- Phase 3: h1 @ W2T, K=256 single pass. 8 waves: w&1 -> mt half (6),
  // w>>1 -> nt quarter. ----
  const int mtb = (w & 1) * 6;   // mt base (6 tiles)
  const int q = w >> 1;          // nt quarter
  f32x4 acc[6][4] = {};
  for (int ks = 0; ks < 8; ++ks) {
    const int k = ks * 32 + quad * 8;
    bf16x8 af[6], bfr[4];
    for (int mt = 0; mt < 6; ++mt)
      af[mt] = *(const bf16x8*)(&h1[(mtb + mt) * 16 + col][k]);
    for (int nt = 0; nt < 4; ++nt) {
      const int n = q * 64 + nt * 16 + col;
      bfr[nt] = *(const bf16x8*)(W2T + (size_t)n * 256 + k);
    }
    for (int mt = 0; mt < 6; ++mt)
      for (int nt = 0; nt < 4; ++nt)
        acc[mt][nt] = MFMA16(af[mt], bfr[nt], acc[mt][nt]);
  }
  __syncthreads();   // MFMAs done; h1 dead -> S/Ag/red may overlay

  // ---- Epilogue: tile-column sums of relu(acc + b2) -> S ----
  for (int nt = 0; nt < 4; ++nt) {
    const int n = q * 64 + nt * 16 + col;
    const float b2c = b2[n];
    float sctx = 0.0f;
    for (int mt = 0; mt < 6; ++mt) {
      const int gm = mtb + mt;
      float s = 0.0f;
      for (int reg = 0; reg < 4; ++reg) {
        const int row = gm * 16 + quad * 4 + reg;
        if (row < 56 || row >= 64) s += fmaxf(acc[mt][nt][reg] + b2c, 0.0f);
      }
      s += __shfl_xor(s, 16);
      s += __shfl_xor(s, 32);
      if (gm < 4) {
        sctx += s;                       // only waves with mtb==0
      } else if (lane < 16) {
        S[1 + (gm - 4)][n] = s;
      }
    }
    if (mtb == 0 && lane < 16) S[0][n] = sctx;
  }
  __syncthreads();
  // Ag rows 0..7 = bf16 agg for each choice; rows 8..15 zero (M=16 pad)
  {
    const int ch = t >> 6;
    const int n0 = (t & 63) * 4;
    bf16x4 y;
    for (int e = 0; e < 4; ++e)
      y[e] = (bf16_t)((S[0][n0 + e] + S[1 + ch][n0 + e]) * (1.0f / 72.0f));
    *(bf16x4*)(&Ag[ch][n0]) = y;
    *(bf16x4*)(&Ag[8 + ch][n0]) = (bf16x4)0.0f;
  }
  __syncthreads();
  // f_phi: g = relu(Ag@W3+b3); score = g@W4 + b4. wave w -> n in [w*32,+32).
  f32x4 acc2[2] = {};
  for (int ks = 0; ks < 8; ++ks) {
    const int k = ks * 32 + quad * 8;
    const bf16x8 af = *(const bf16x8*)(&Ag[col][k]);
    for (int nt = 0; nt < 2; ++nt) {
      const int n = w * 32 + nt * 16 + col;
      const bf16x8 bfr = *(const bf16x8*)(W3T + (size_t)n * 256 + k);
      acc2[nt] = MFMA16(af, bfr, acc2[nt]);
    }
  }
  for (int reg = 0; reg < 4; ++reg) {
    float pr = 0.0f;
    for (int nt = 0; nt < 2; ++nt) {
      const int n = w * 32 + nt * 16 + col;
      pr += fmaxf(acc2[nt][reg] + b3[n], 0.0f) * W4[n];
    }
    pr += __shfl_xor(pr, 1);
    pr += __shfl_xor(pr, 2);
    pr += __shfl_xor(pr, 4);
    pr += __shfl_xor(pr, 8);
    if (col == 0 && quad < 2) red[w][quad * 4 + reg] = pr;  // rows 8..15 dropped
  }
  __syncthreads();
  if (t < 8) {
    float sc = b4[0];
    for (int ww = 0; ww < 8; ++ww) sc += red[ww][t];
    out[b * 8 + t] = sc;
  }
}

extern "C" void kernel_launch(void* const* d_in, const int* in_sizes, int n_in,
                              void* d_out, int out_size, void* d_ws, size_t ws_size,
                              hipStream_t stream) {
  (void)in_sizes; (void)n_in; (void)out_size; (void)ws_size;
  const float* ctx = (const float*)d_in[0];
  const float* cho = (const float*)d_in[1];
  const float* W1  = (const float*)d_in[2];
  const float* b1  = (const float*)d_in[3];
  const float* W2  = (const float*)d_in[4];
  const float* b2  = (const float*)d_in[5];
  const float* W3  = (const float*)d_in[6];
  const float* b3  = (const float*)d_in[7];
  const float* W4  = (const float*)d_in[8];
  const float* b4  = (const float*)d_in[9];
  char* ws = (char*)d_ws;
  bf16_t* Wp   = (bf16_t*)(ws + 0);
  bf16_t* W2T  = (bf16_t*)(ws + 524288);
  bf16_t* W3T  = (bf16_t*)(ws + 655360);
  float*  out  = (float*)d_out;

  void* args[] = {&ctx, &cho, &W1, &W2, &W3, &Wp, &W2T, &W3T,
                  &b1, &b2, &b3, &W4, &b4, &out};
  hipLaunchCooperativeKernel((const void*)fused_kernel, dim3(256), dim3(512),
                             args, 0, stream);
}

// Round 3
// 107.830 us; speedup vs baseline: 1.5957x; 1.5957x over previous
//
#include <hip/hip_runtime.h>
#include <hip/hip_bf16.h>

// RelationNetwork fused pipeline, bf16 MFMA (gfx950).
//
// r11: revert to the three-kernel r0 structure (best measured: 109.7us).
// r2's cooperative grid.sync cost ~55us on this chip (8-XCD device-scope
// barrier) -- never again for latency-class kernels.
// Single change vs r0: k2 phase-3 B-operand (W2T) is now staged into LDS
// by the otherwise-idle threads 384..511 during the h1 staging phase.
// Halves W2T L2 traffic (256->128 KB/block) and turns the MFMA loop's
// global loads into ds_read_b128.
//
// Factorizations:
//  (1) pair@W1 = u[i]+v[j]  -> one 4096x512x512 GEMM (K1).
//  (2) ctx-ctx pair sum is choice-invariant -> computed once per b inside K2.
//  (3) f_phi fused into K2 (agg rows live in LDS; no K3, no aggb round-trip).
//  (4) K1 stages fp32 X into a shared LDS bf16 A-tile.
//  (5) UV stored bf16 (halves UV write + K2 staging traffic).
//  (6) prep via LDS 64x64 tile transpose (coalesced both sides).
//
// ws layout (bytes):
//   [0,        524288)   Wp   bf16 [512][512]  Wp[j][k]=W1'[k][j]
//   [524288,   655360)   W2T  bf16 [256][256]
//   [655360,   786432)   W3T  bf16 [256][256]
//   [786432,   4980736)  UV   bf16 [4096][512] row b*16+p; cols 0..255=u, 256..511=v

typedef __bf16 bf16_t;
typedef bf16_t bf16x8 __attribute__((ext_vector_type(8)));
typedef bf16_t bf16x4 __attribute__((ext_vector_type(4)));
typedef float f32x4 __attribute__((ext_vector_type(4)));

#define MFMA16(a, b, c) __builtin_amdgcn_mfma_f32_16x16x32_bf16((a), (b), (c), 0, 0, 0)

// ---- K0: weight transposes via LDS tiles (96 blocks x 256 thr) -------------
// All sources have leading dim 256. Ts fp32 [64][65]: transpose-read bank
// stride 65%32=1 -> 2-way only. Reads 256 B coalesced, writes 128 B coalesced.
__global__ __launch_bounds__(256) void prep_kernel(
    const float* __restrict__ W1, const float* __restrict__ W2,
    const float* __restrict__ W3, bf16_t* __restrict__ Wp,
    bf16_t* __restrict__ W2T, bf16_t* __restrict__ W3T) {
  __shared__ float Ts[64][65];
  const int b = blockIdx.x;
  const int t = threadIdx.x;
  const int r = t >> 6;          // 0..3
  const int c = t & 63;
  const float* srcP;
  bf16_t* dstP;
  int srcRow, srcCol, dr0, dc0, dstride;
  if (b < 64) {                  // Wp tile: tk = b>>3, tj = b&7
    const int k0 = (b >> 3) * 64, j0 = (b & 7) * 64;
    srcP = W1; dstP = Wp; dstride = 512;
    srcRow = (j0 < 256) ? k0 : 512 + k0;
    srcCol = (j0 < 256) ? j0 : j0 - 256;
    dr0 = j0; dc0 = k0;
  } else if (b < 80) {           // W2T tile
    const int s = b - 64;
    const int k0 = (s >> 2) * 64, n0 = (s & 3) * 64;
    srcP = W2; dstP = W2T; dstride = 256;
    srcRow = k0; srcCol = n0; dr0 = n0; dc0 = k0;
  } else {                       // W3T tile
    const int s = b - 80;
    const int k0 = (s >> 2) * 64, n0 = (s & 3) * 64;
    srcP = W3; dstP = W3T; dstride = 256;
    srcRow = k0; srcCol = n0; dr0 = n0; dc0 = k0;
  }
  for (int i = 0; i < 16; ++i) {           // 16 iters x 4 rows = 64 rows
    const int a = i * 4 + r;
    Ts[a][c] = srcP[(size_t)(srcRow + a) * 256 + srcCol + c];
  }
  __syncthreads();
  for (int i = 0; i < 16; ++i) {
    const int j = i * 4 + r;
    dstP[(size_t)(dr0 + j) * dstride + dc0 + c] = (bf16_t)Ts[c][j];
  }
}

// ---- K1: UV = X @ Wp^T  (M=4096, N=512, K=512), bf16 output ----------------
// 256 blocks = 64 Mtiles(64) x 4 Ntiles(128); 512 thr = 8 waves (4mt x 1nt).
// A-tile staged fp32->bf16 into LDS once per block (8 waves share), two K=256
// halves; staging 8 threads/row, 16B chunks, fully coalesced 128 B groups.
__global__ __launch_bounds__(512) void k1_kernel(
    const float* __restrict__ ctx, const float* __restrict__ cho,
    const bf16_t* __restrict__ Wp, bf16_t* __restrict__ UV) {
  __shared__ bf16_t As[64][264];           // 33.8 KB; row bank-stride 4 -> 2-way max
  const int bm = blockIdx.x & 63;
  const int bn = blockIdx.x >> 6;          // 0..3
  const int t = threadIdx.x;
  const int lane = t & 63;
  const int w = t >> 6;                    // 0..7
  const int col = lane & 15;
  const int quad = lane >> 4;
  const int n = bn * 128 + w * 16 + col;
  // staging role: row sr (8 threads/row), column base cb
  const int sr = t >> 3;                   // 0..63
  const int gr = bm * 64 + sr;             // X row = b*16 + p
  const int bi = gr >> 4;
  const int p = gr & 15;
  const float* src = (p < 8) ? ctx + (size_t)(bi * 8 + p) * 512
                             : cho + (size_t)(bi * 8 + (p - 8)) * 512;
  const int cb = (t & 7) * 4;
  f32x4 acc[4] = {};
  for (int half = 0; half < 2; ++half) {
    const int kbase = half * 256;
    for (int i = 0; i < 8; ++i) {
      const int c = cb + i * 32;
      const f32x4 x = *(const f32x4*)(src + kbase + c);
      bf16x4 y;
      for (int e = 0; e < 4; ++e) y[e] = (bf16_t)x[e];
      *(bf16x4*)(&As[sr][c]) = y;
    }
    __syncthreads();
    for (int ks = 0; ks < 8; ++ks) {
      const int k = ks * 32 + quad * 8;
      bf16x8 af[4];
      for (int mt = 0; mt < 4; ++mt)
        af[mt] = *(const bf16x8*)(&As[mt * 16 + col][k]);
      const bf16x8 bf = *(const bf16x8*)(Wp + (size_t)n * 512 + kbase + k);
      for (int mt = 0; mt < 4; ++mt) acc[mt] = MFMA16(af[mt], bf, acc[mt]);
    }
    __syncthreads();
  }
  for (int mt = 0; mt < 4; ++mt)
    for (int reg = 0; reg < 4; ++reg) {
      const int r = bm * 64 + mt * 16 + quad * 4 + reg;
      UV[(size_t)r * 512 + n] = (bf16_t)acc[mt][reg];
    }
}

// ---- K2: merged relation stage + f_phi. One block per b (256 blk, 512 thr).
// Rows r in [0,192): r<56 ctx pair; 56..63 zero pad; r=64+ch*16+rr choice pair.
// h1 staged in LDS in two K=128 phases. While threads 0..383 stage h1,
// threads 384..511 (otherwise idle) stage the W2T K-half into W2s: phase-3
// B-fragments become ds_read_b128 (halves W2T L2 traffic, kills VMEM latency
// in the MFMA loop). 8 waves: w&1 -> mt half (6), w>>1 -> nt quarter.
// Then (LDS overlay, h1 dead): S[9][256] column sums -> Ag[16][264] bf16 agg
// rows -> f_phi MFMA vs W3T -> W4 dot -> out[b*8+ch].
//
// LDS map (121856 B):
//   [0,     52224)  h1  bf16 [192][136]
//     overlays (h1 dead): S f32[9][256] @0; Ag bf16[16][264] @9216; red @17664
//   [52224, 121856) W2s bf16 [256][136]  (cols 0..127 used; 272 B rows, 16-B
//                                          aligned; stride-1-row reads -> <=2-way)
__global__ __launch_bounds__(512) void k2_kernel(
    const bf16_t* __restrict__ UV, const float* __restrict__ b1,
    const float* __restrict__ b2, const bf16_t* __restrict__ W2T,
    const bf16_t* __restrict__ W3T, const float* __restrict__ b3,
    const float* __restrict__ W4, const float* __restrict__ b4,
    float* __restrict__ out) {
  __shared__ char smem[121856];
  bf16_t (*h1)[136] = (bf16_t(*)[136])smem;
  bf16_t (*W2s)[136] = (bf16_t(*)[136])(smem + 52224);
  float (*S)[256] = (float(*)[256])smem;            // 9216 B (after h1 dead)
  bf16_t (*Ag)[264] = (bf16_t(*)[264])(smem + 9216);   // 8448 B
  float (*red)[8] = (float(*)[8])(smem + 9216 + 8448); // 256 B
  const int b = blockIdx.x;
  const int t = threadIdx.x;
  const int lane = t & 63;
  const int w = t >> 6;
  const int col = lane & 15;
  const int quad = lane >> 4;
  // staging role (threads 0..383: 2 per row)
  const bf16_t* su = nullptr;
  const bf16_t* sv = nullptr;
  int sr = 0, sc0 = 0;
  if (t < 384) {
    sr = t >> 1;
    sc0 = (t & 1) * 64;
    if (sr < 56) {
      const int i = sr / 7;
      const int jj = sr - i * 7;
      const int j = jj + (jj >= i ? 1 : 0);
      su = UV + (size_t)(b * 16 + i) * 512;
      sv = UV + (size_t)(b * 16 + j) * 512 + 256;
    } else if (sr >= 64) {
      const int ch = (sr - 64) >> 4;
      const int rr = (sr - 64) & 15;
      if (rr < 8) {
        su = UV + (size_t)(b * 16 + 8 + ch) * 512;
        sv = UV + (size_t)(b * 16 + rr) * 512 + 256;
      } else {
        su = UV + (size_t)(b * 16 + (rr - 8)) * 512;
        sv = UV + (size_t)(b * 16 + 8 + ch) * 512 + 256;
      }
    }
  }
  const int mtb = (w & 1) * 6;   // mt base (6 tiles)
  const int q = w >> 1;          // nt quarter
  f32x4 acc[6][4] = {};
  for (int half = 0; half < 2; ++half) {
    const int kbase = half * 128;
    if (t < 384) {
      if (su) {
        for (int c = sc0; c < sc0 + 64; c += 8) {
          const bf16x8 u8 = *(const bf16x8*)(su + kbase + c);
          const bf16x8 v8 = *(const bf16x8*)(sv + kbase + c);
          const f32x4 bb0 = *(const f32x4*)(b1 + kbase + c);
          const f32x4 bb1 = *(const f32x4*)(b1 + kbase + c + 4);
          bf16x8 y;
          for (int e = 0; e < 4; ++e)
            y[e] = (bf16_t)fmaxf((float)u8[e] + (float)v8[e] + bb0[e], 0.0f);
          for (int e = 0; e < 4; ++e)
            y[4 + e] = (bf16_t)fmaxf((float)u8[4 + e] + (float)v8[4 + e] + bb1[e], 0.0f);
          *(bf16x8*)(&h1[sr][c]) = y;
        }
      } else if (half == 0) {    // zero-pad rows 56..63 once; nothing overwrites
        for (int c = sc0; c < sc0 + 64; c += 8)
          *(bf16x8*)(&h1[sr][c]) = (bf16x8)0.0f;
      }
    } else {
      // stage W2T K-half -> W2s: 128 thr x 2 rows x 128 cols (16 B chunks,
      // 256 B contiguous per row per thread)
      const int n0 = (t - 384) * 2;
      for (int rr = 0; rr < 2; ++rr) {
        const bf16_t* srcw = W2T + (size_t)(n0 + rr) * 256 + kbase;
        for (int cc = 0; cc < 128; cc += 8)
          *(bf16x8*)(&W2s[n0 + rr][cc]) = *(const bf16x8*)(srcw + cc);
      }
    }
    __syncthreads();
    for (int ks = 0; ks < 4; ++ks) {
      const int k = ks * 32 + quad * 8;  // within-phase k, <128
      bf16x8 af[6], bfr[4];
      for (int mt = 0; mt < 6; ++mt)
        af[mt] = *(const bf16x8*)(&h1[(mtb + mt) * 16 + col][k]);
      for (int nt = 0; nt < 4; ++nt) {
        const int n = q * 64 + nt * 16 + col;
        bfr[nt] = *(const bf16x8*)(&W2s[n][k]);
      }
      for (int mt = 0; mt < 6; ++mt)
        for (int nt = 0; nt < 4; ++nt)
          acc[mt][nt] = MFMA16(af[mt], bfr[nt], acc[mt][nt]);
    }
    __syncthreads();   // MFMAs done; h1/W2s safe to overwrite next half
  }
  // epilogue: tile-column sums of relu(acc + b2) -> S (overlays h1)
  for (int nt = 0; nt < 4; ++nt) {
    const int n = q * 64 + nt * 16 + col;
    const float b2c = b2[n];
    float sctx = 0.0f;
    for (int mt = 0; mt < 6; ++mt) {
      const int gm = mtb + mt;
      float s = 0.0f;
      for (int reg = 0; reg < 4; ++reg) {
        const int row = gm * 16 + quad * 4 + reg;
        if (row < 56 || row >= 64) s += fmaxf(acc[mt][nt][reg] + b2c, 0.0f);
      }
      s += __shfl_xor(s, 16);
      s += __shfl_xor(s, 32);
      if (gm < 4) {
        sctx += s;                       // only waves with mtb==0
      } else if (lane < 16) {
        S[1 + (gm - 4)][n] = s;
      }
    }
    if (mtb == 0 && lane < 16) S[0][n] = sctx;
  }
  __syncthreads();
  // Ag rows 0..7 = bf16 agg for each choice; rows 8..15 zero (M=16 pad)
  {
    const int ch = t >> 6;
    const int n0 = (t & 63) * 4;
    bf16x4 y;
    for (int e = 0; e < 4; ++e)
      y[e] = (bf16_t)((S[0][n0 + e] + S[1 + ch][n0 + e]) * (1.0f / 72.0f));
    *(bf16x4*)(&Ag[ch][n0]) = y;
    *(bf16x4*)(&Ag[8 + ch][n0]) = (bf16x4)0.0f;
  }
  __syncthreads();
  // f_phi: g = relu(Ag@W3+b3); score = g@W4 + b4. wave w -> n in [w*32,+32).
  f32x4 acc2[2] = {};
  for (int ks = 0; ks < 8; ++ks) {
    const int k = ks * 32 + quad * 8;
    const bf16x8 af = *(const bf16x8*)(&Ag[col][k]);
    for (int nt = 0; nt < 2; ++nt) {
      const int n = w * 32 + nt * 16 + col;
      const bf16x8 bfr = *(const bf16x8*)(W3T + (size_t)n * 256 + k);
      acc2[nt] = MFMA16(af, bfr, acc2[nt]);
    }
  }
  for (int reg = 0; reg < 4; ++reg) {
    float pr = 0.0f;
    for (int nt = 0; nt < 2; ++nt) {
      const int n = w * 32 + nt * 16 + col;
      pr += fmaxf(acc2[nt][reg] + b3[n], 0.0f) * W4[n];
    }
    pr += __shfl_xor(pr, 1);
    pr += __shfl_xor(pr, 2);
    pr += __shfl_xor(pr, 4);
    pr += __shfl_xor(pr, 8);
    if (col == 0 && quad < 2) red[w][quad * 4 + reg] = pr;  // rows 8..15 dropped
  }
  __syncthreads();
  if (t < 8) {
    float sc = b4[0];
    for (int ww = 0; ww < 8; ++ww) sc += red[ww][t];
    out[b * 8 + t] = sc;
  }
}

extern "C" void kernel_launch(void* const* d_in, const int* in_sizes, int n_in,
                              void* d_out, int out_size, void* d_ws, size_t ws_size,
                              hipStream_t stream) {
  (void)in_sizes; (void)n_in; (void)out_size; (void)ws_size;
  const float* ctx = (const float*)d_in[0];
  const float* cho = (const float*)d_in[1];
  const float* W1  = (const float*)d_in[2];
  const float* b1  = (const float*)d_in[3];
  const float* W2  = (const float*)d_in[4];
  const float* b2  = (const float*)d_in[5];
  const float* W3  = (const float*)d_in[6];
  const float* b3  = (const float*)d_in[7];
  const float* W4  = (const float*)d_in[8];
  const float* b4  = (const float*)d_in[9];
  char* ws = (char*)d_ws;
  bf16_t* Wp   = (bf16_t*)(ws + 0);
  bf16_t* W2T  = (bf16_t*)(ws + 524288);
  bf16_t* W3T  = (bf16_t*)(ws + 655360);
  bf16_t* UV   = (bf16_t*)(ws + 786432);
  float*  out  = (float*)d_out;

  prep_kernel<<<dim3(96), dim3(256), 0, stream>>>(W1, W2, W3, Wp, W2T, W3T);
  k1_kernel<<<dim3(256), dim3(512), 0, stream>>>(ctx, cho, Wp, UV);
  k2_kernel<<<dim3(256), dim3(512), 0, stream>>>(UV, b1, b2, W2T, W3T, b3, W4, b4, out);
}

// Round 4
// 104.975 us; speedup vs baseline: 1.6391x; 1.0272x over previous
//
#include <hip/hip_runtime.h>
#include <hip/hip_bf16.h>

// RelationNetwork fused pipeline, bf16 MFMA (gfx950).
//
// r12 (= r3 best + one change): k2 now stages its 16KB UV tile into LDS
// once at kernel start; the h1 build reads u/v from LDS instead of making
// ~196 KB/block of redundant latency-bound L2 reads (12x re-read of the
// tile via the 72-pair expansion). Everything else identical to r3
// (107.8us): 3-kernel structure, W2T staged in LDS by threads 384..511,
// f_phi fused into k2.
//
// Factorizations:
//  (1) pair@W1 = u[i]+v[j]  -> one 4096x512x512 GEMM (K1).
//  (2) ctx-ctx pair sum is choice-invariant -> computed once per b inside K2.
//  (3) f_phi fused into K2 (agg rows live in LDS; no K3, no aggb round-trip).
//  (4) K1 stages fp32 X into a shared LDS bf16 A-tile.
//  (5) UV stored bf16 (halves UV write + K2 staging traffic).
//  (6) prep via LDS 64x64 tile transpose (coalesced both sides).
//
// ws layout (bytes):
//   [0,        524288)   Wp   bf16 [512][512]  Wp[j][k]=W1'[k][j]
//   [524288,   655360)   W2T  bf16 [256][256]
//   [655360,   786432)   W3T  bf16 [256][256]
//   [786432,   4980736)  UV   bf16 [4096][512] row b*16+p; cols 0..255=u, 256..511=v

typedef __bf16 bf16_t;
typedef bf16_t bf16x8 __attribute__((ext_vector_type(8)));
typedef bf16_t bf16x4 __attribute__((ext_vector_type(4)));
typedef float f32x4 __attribute__((ext_vector_type(4)));

#define MFMA16(a, b, c) __builtin_amdgcn_mfma_f32_16x16x32_bf16((a), (b), (c), 0, 0, 0)

// ---- K0: weight transposes via LDS tiles (96 blocks x 256 thr) -------------
// All sources have leading dim 256. Ts fp32 [64][65]: transpose-read bank
// stride 65%32=1 -> 2-way only. Reads 256 B coalesced, writes 128 B coalesced.
__global__ __launch_bounds__(256) void prep_kernel(
    const float* __restrict__ W1, const float* __restrict__ W2,
    const float* __restrict__ W3, bf16_t* __restrict__ Wp,
    bf16_t* __restrict__ W2T, bf16_t* __restrict__ W3T) {
  __shared__ float Ts[64][65];
  const int b = blockIdx.x;
  const int t = threadIdx.x;
  const int r = t >> 6;          // 0..3
  const int c = t & 63;
  const float* srcP;
  bf16_t* dstP;
  int srcRow, srcCol, dr0, dc0, dstride;
  if (b < 64) {                  // Wp tile: tk = b>>3, tj = b&7
    const int k0 = (b >> 3) * 64, j0 = (b & 7) * 64;
    srcP = W1; dstP = Wp; dstride = 512;
    srcRow = (j0 < 256) ? k0 : 512 + k0;
    srcCol = (j0 < 256) ? j0 : j0 - 256;
    dr0 = j0; dc0 = k0;
  } else if (b < 80) {           // W2T tile
    const int s = b - 64;
    const int k0 = (s >> 2) * 64, n0 = (s & 3) * 64;
    srcP = W2; dstP = W2T; dstride = 256;
    srcRow = k0; srcCol = n0; dr0 = n0; dc0 = k0;
  } else {                       // W3T tile
    const int s = b - 80;
    const int k0 = (s >> 2) * 64, n0 = (s & 3) * 64;
    srcP = W3; dstP = W3T; dstride = 256;
    srcRow = k0; srcCol = n0; dr0 = n0; dc0 = k0;
  }
  for (int i = 0; i < 16; ++i) {           // 16 iters x 4 rows = 64 rows
    const int a = i * 4 + r;
    Ts[a][c] = srcP[(size_t)(srcRow + a) * 256 + srcCol + c];
  }
  __syncthreads();
  for (int i = 0; i < 16; ++i) {
    const int j = i * 4 + r;
    dstP[(size_t)(dr0 + j) * dstride + dc0 + c] = (bf16_t)Ts[c][j];
  }
}

// ---- K1: UV = X @ Wp^T  (M=4096, N=512, K=512), bf16 output ----------------
// 256 blocks = 64 Mtiles(64) x 4 Ntiles(128); 512 thr = 8 waves (4mt x 1nt).
// A-tile staged fp32->bf16 into LDS once per block (8 waves share), two K=256
// halves; staging 8 threads/row, 16B chunks, fully coalesced 128 B groups.
__global__ __launch_bounds__(512) void k1_kernel(
    const float* __restrict__ ctx, const float* __restrict__ cho,
    const bf16_t* __restrict__ Wp, bf16_t* __restrict__ UV) {
  __shared__ bf16_t As[64][264];           // 33.8 KB; row bank-stride 4 -> 2-way max
  const int bm = blockIdx.x & 63;
  const int bn = blockIdx.x >> 6;          // 0..3
  const int t = threadIdx.x;
  const int lane = t & 63;
  const int w = t >> 6;                    // 0..7
  const int col = lane & 15;
  const int quad = lane >> 4;
  const int n = bn * 128 + w * 16 + col;
  // staging role: row sr (8 threads/row), column base cb
  const int sr = t >> 3;                   // 0..63
  const int gr = bm * 64 + sr;             // X row = b*16 + p
  const int bi = gr >> 4;
  const int p = gr & 15;
  const float* src = (p < 8) ? ctx + (size_t)(bi * 8 + p) * 512
                             : cho + (size_t)(bi * 8 + (p - 8)) * 512;
  const int cb = (t & 7) * 4;
  f32x4 acc[4] = {};
  for (int half = 0; half < 2; ++half) {
    const int kbase = half * 256;
    for (int i = 0; i < 8; ++i) {
      const int c = cb + i * 32;
      const f32x4 x = *(const f32x4*)(src + kbase + c);
      bf16x4 y;
      for (int e = 0; e < 4; ++e) y[e] = (bf16_t)x[e];
      *(bf16x4*)(&As[sr][c]) = y;
    }
    __syncthreads();
    for (int ks = 0; ks < 8; ++ks) {
      const int k = ks * 32 + quad * 8;
      bf16x8 af[4];
      for (int mt = 0; mt < 4; ++mt)
        af[mt] = *(const bf16x8*)(&As[mt * 16 + col][k]);
      const bf16x8 bf = *(const bf16x8*)(Wp + (size_t)n * 512 + kbase + k);
      for (int mt = 0; mt < 4; ++mt) acc[mt] = MFMA16(af[mt], bf, acc[mt]);
    }
    __syncthreads();
  }
  for (int mt = 0; mt < 4; ++mt)
    for (int reg = 0; reg < 4; ++reg) {
      const int r = bm * 64 + mt * 16 + quad * 4 + reg;
      UV[(size_t)r * 512 + n] = (bf16_t)acc[mt][reg];
    }
}

// ---- K2: merged relation stage + f_phi. One block per b (256 blk, 512 thr).
// Phase 0: stage UV tile [16][512] -> UVs (LDS, 16KB, one coalesced round).
// Phase 1/2 (x2 K-halves): threads 0..383 build h1 = relu(u[i]+v[j]+b1) from
// UVs (LDS reads; same-row lanes broadcast); threads 384..511 stage the W2T
// K-half into W2s. Then MFMA h1 @ W2s.
// Rows r in [0,192): r<56 ctx pair; 56..63 zero pad; r=64+ch*16+rr choice pair.
// Epilogue (overlays, UVs/h1 dead): S[9][256] column sums -> Ag[16][264] bf16
// agg rows -> f_phi MFMA vs W3T -> W4 dot -> out[b*8+ch].
//
// LDS map (138496 B):
//   [0,     16640)  UVs bf16 [16][520]  (row stride 260dw%32=4: 8-row full
//                                         bank cycle -> <=2-way on reads)
//   [16640, 68864)  h1  bf16 [192][136]
//   [68864, 138496) W2s bf16 [256][136] (cols 0..127 used)
//   overlays: S f32[9][256] @0 (UVs dead); Ag bf16[16][264] @16640 (h1 dead);
//             red f32[8][8] @25088
__global__ __launch_bounds__(512) void k2_kernel(
    const bf16_t* __restrict__ UV, const float* __restrict__ b1,
    const float* __restrict__ b2, const bf16_t* __restrict__ W2T,
    const bf16_t* __restrict__ W3T, const float* __restrict__ b3,
    const float* __restrict__ W4, const float* __restrict__ b4,
    float* __restrict__ out) {
  __shared__ char smem[138496];
  bf16_t (*UVs)[520] = (bf16_t(*)[520])smem;
  bf16_t (*h1)[136]  = (bf16_t(*)[136])(smem + 16640);
  bf16_t (*W2s)[136] = (bf16_t(*)[136])(smem + 68864);
  float  (*S)[256]   = (float(*)[256])smem;                 // UVs dead
  bf16_t (*Ag)[264]  = (bf16_t(*)[264])(smem + 16640);      // h1 dead
  float  (*red)[8]   = (float(*)[8])(smem + 16640 + 8448);
  const int b = blockIdx.x;
  const int t = threadIdx.x;
  const int lane = t & 63;
  const int w = t >> 6;
  const int col = lane & 15;
  const int quad = lane >> 4;

  // ---- Phase 0: stage UV tile -> UVs. 32 thr/row, 32 B each, coalesced. ----
  {
    const int row = t >> 5;          // 0..15
    const int c0 = (t & 31) * 16;
    const bf16_t* src = UV + (size_t)(b * 16 + row) * 512 + c0;
    *(bf16x8*)(&UVs[row][c0]) = *(const bf16x8*)(src);
    *(bf16x8*)(&UVs[row][c0 + 8]) = *(const bf16x8*)(src + 8);
  }
  // staging role (threads 0..383: 2 per row); su/sv point into UVs (LDS)
  const bf16_t* su = nullptr;
  const bf16_t* sv = nullptr;
  int sr = 0, sc0 = 0;
  if (t < 384) {
    sr = t >> 1;
    sc0 = (t & 1) * 64;
    if (sr < 56) {
      const int i = sr / 7;
      const int jj = sr - i * 7;
      const int j = jj + (jj >= i ? 1 : 0);
      su = UVs[i];
      sv = UVs[j] + 256;
    } else if (sr >= 64) {
      const int ch = (sr - 64) >> 4;
      const int rr = (sr - 64) & 15;
      if (rr < 8) { su = UVs[8 + ch]; sv = UVs[rr] + 256; }
      else        { su = UVs[rr - 8]; sv = UVs[8 + ch] + 256; }
    }
  }
  __syncthreads();   // UVs ready

  const int mtb = (w & 1) * 6;   // mt base (6 tiles)
  const int q = w >> 1;          // nt quarter
  f32x4 acc[6][4] = {};
  for (int half = 0; half < 2; ++half) {
    const int kbase = half * 128;
    if (t < 384) {
      if (su) {
        for (int c = sc0; c < sc0 + 64; c += 8) {
          const bf16x8 u8 = *(const bf16x8*)(su + kbase + c);
          const bf16x8 v8 = *(const bf16x8*)(sv + kbase + c);
          const f32x4 bb0 = *(const f32x4*)(b1 + kbase + c);
          const f32x4 bb1 = *(const f32x4*)(b1 + kbase + c + 4);
          bf16x8 y;
          for (int e = 0; e < 4; ++e)
            y[e] = (bf16_t)fmaxf((float)u8[e] + (float)v8[e] + bb0[e], 0.0f);
          for (int e = 0; e < 4; ++e)
            y[4 + e] = (bf16_t)fmaxf((float)u8[4 + e] + (float)v8[4 + e] + bb1[e], 0.0f);
          *(bf16x8*)(&h1[sr][c]) = y;
        }
      } else if (half == 0) {    // zero-pad rows 56..63 once; nothing overwrites
        for (int c = sc0; c < sc0 + 64; c += 8)
          *(bf16x8*)(&h1[sr][c]) = (bf16x8)0.0f;
      }
    } else {
      // stage W2T K-half -> W2s: 128 thr x 2 rows x 128 cols (16 B chunks,
      // 256 B contiguous per row per thread)
      const int n0 = (t - 384) * 2;
      for (int rr = 0; rr < 2; ++rr) {
        const bf16_t* srcw = W2T + (size_t)(n0 + rr) * 256 + kbase;
        for (int cc = 0; cc < 128; cc += 8)
          *(bf16x8*)(&W2s[n0 + rr][cc]) = *(const bf16x8*)(srcw + cc);
      }
    }
    __syncthreads();
    for (int ks = 0; ks < 4; ++ks) {
      const int k = ks * 32 + quad * 8;  // within-phase k, <128
      bf16x8 af[6], bfr[4];
      for (int mt = 0; mt < 6; ++mt)
        af[mt] = *(const bf16x8*)(&h1[(mtb + mt) * 16 + col][k]);
      for (int nt = 0; nt < 4; ++nt) {
        const int n = q * 64 + nt * 16 + col;
        bfr[nt] = *(const bf16x8*)(&W2s[n][k]);
      }
      for (int mt = 0; mt < 6; ++mt)
        for (int nt = 0; nt < 4; ++nt)
          acc[mt][nt] = MFMA16(af[mt], bfr[nt], acc[mt][nt]);
    }
    __syncthreads();   // MFMAs done; h1/W2s safe to overwrite next half
  }
  // epilogue: tile-column sums of relu(acc + b2) -> S (overlays UVs)
  for (int nt = 0; nt < 4; ++nt) {
    const int n = q * 64 + nt * 16 + col;
    const float b2c = b2[n];
    float sctx = 0.0f;
    for (int mt = 0; mt < 6; ++mt) {
      const int gm = mtb + mt;
      float s = 0.0f;
      for (int reg = 0; reg < 4; ++reg) {
        const int row = gm * 16 + quad * 4 + reg;
        if (row < 56 || row >= 64) s += fmaxf(acc[mt][nt][reg] + b2c, 0.0f);
      }
      s += __shfl_xor(s, 16);
      s += __shfl_xor(s, 32);
      if (gm < 4) {
        sctx += s;                       // only waves with mtb==0
      } else if (lane < 16) {
        S[1 + (gm - 4)][n] = s;
      }
    }
    if (mtb == 0 && lane < 16) S[0][n] = sctx;
  }
  __syncthreads();
  // Ag rows 0..7 = bf16 agg for each choice; rows 8..15 zero (M=16 pad)
  {
    const int ch = t >> 6;
    const int n0 = (t & 63) * 4;
    bf16x4 y;
    for (int e = 0; e < 4; ++e)
      y[e] = (bf16_t)((S[0][n0 + e] + S[1 + ch][n0 + e]) * (1.0f / 72.0f));
    *(bf16x4*)(&Ag[ch][n0]) = y;
    *(bf16x4*)(&Ag[8 + ch][n0]) = (bf16x4)0.0f;
  }
  __syncthreads();
  // f_phi: g = relu(Ag@W3+b3); score = g@W4 + b4. wave w -> n in [w*32,+32).
  f32x4 acc2[2] = {};
  for (int ks = 0; ks < 8; ++ks) {
    const int k = ks * 32 + quad * 8;
    const bf16x8 af = *(const bf16x8*)(&Ag[col][k]);
    for (int nt = 0; nt < 2; ++nt) {
      const int n = w * 32 + nt * 16 + col;
      const bf16x8 bfr = *(const bf16x8*)(W3T + (size_t)n * 256 + k);
      acc2[nt] = MFMA16(af, bfr, acc2[nt]);
    }
  }
  for (int reg = 0; reg < 4; ++reg) {
    float pr = 0.0f;
    for (int nt = 0; nt < 2; ++nt) {
      const int n = w * 32 + nt * 16 + col;
      pr += fmaxf(acc2[nt][reg] + b3[n], 0.0f) * W4[n];
    }
    pr += __shfl_xor(pr, 1);
    pr += __shfl_xor(pr, 2);
    pr += __shfl_xor(pr, 4);
    pr += __shfl_xor(pr, 8);
    if (col == 0 && quad < 2) red[w][quad * 4 + reg] = pr;  // rows 8..15 dropped
  }
  __syncthreads();
  if (t < 8) {
    float sc = b4[0];
    for (int ww = 0; ww < 8; ++ww) sc += red[ww][t];
    out[b * 8 + t] = sc;
  }
}

extern "C" void kernel_launch(void* const* d_in, const int* in_sizes, int n_in,
                              void* d_out, int out_size, void* d_ws, size_t ws_size,
                              hipStream_t stream) {
  (void)in_sizes; (void)n_in; (void)out_size; (void)ws_size;
  const float* ctx = (const float*)d_in[0];
  const float* cho = (const float*)d_in[1];
  const float* W1  = (const float*)d_in[2];
  const float* b1  = (const float*)d_in[3];
  const float* W2  = (const float*)d_in[4];
  const float* b2  = (const float*)d_in[5];
  const float* W3  = (const float*)d_in[6];
  const float* b3  = (const float*)d_in[7];
  const float* W4  = (const float*)d_in[8];
  const float* b4  = (const float*)d_in[9];
  char* ws = (char*)d_ws;
  bf16_t* Wp   = (bf16_t*)(ws + 0);
  bf16_t* W2T  = (bf16_t*)(ws + 524288);
  bf16_t* W3T  = (bf16_t*)(ws + 655360);
  bf16_t* UV   = (bf16_t*)(ws + 786432);
  float*  out  = (float*)d_out;

  prep_kernel<<<dim3(96), dim3(256), 0, stream>>>(W1, W2, W3, Wp, W2T, W3T);
  k1_kernel<<<dim3(256), dim3(512), 0, stream>>>(ctx, cho, Wp, UV);
  k2_kernel<<<dim3(256), dim3(512), 0, stream>>>(UV, b1, b2, W2T, W3T, b3, W4, b4, out);
}